// Round 4
// baseline (3796.969 us; speedup 1.0000x reference)
//
#include <hip/hip_runtime.h>

#define NOISE 100
#define EMB   50
#define CIN1  306   // 256 + 50
#define ALPHA 0.3f
#define BNEPS 1e-3f
#define S1    53    // padded row stride (floats) for 49-wide tiles: conflict-free writes

// scrubbed fp32 load: NaN/inf/garbage -> 0, so ANY wrong-world scenario yields
// finite (diagnosable) output instead of NaN.
__device__ __forceinline__ float ldf(const float* p){
    float v = *p;
    return (v == v && fabsf(v) < 1e30f) ? v : 0.f;
}

// ConvT2 inner: 7x7x256 -> 14x14x128, stride 2, pads (3,2); 98 positions per phase
template<int P0>
__device__ __forceinline__ void conv2_body(const float* xt, const float* wbase, float* acc){
    #pragma unroll 1
    for (int ci = 0; ci < 256; ci++){
        float xr[49];
        #pragma unroll
        for (int q = 0; q < 49; q++) xr[q] = xt[ci*S1 + q];
        const float* wci = wbase + ci*128;
        #pragma unroll
        for (int ky = 0; ky < 5; ky++){
            #pragma unroll
            for (int kx = 0; kx < 5; kx++){
                float w = ldf(wci + (ky*5 + kx)*256*128);
                #pragma unroll
                for (int ii = 0; ii < 98; ii++){
                    int p2 = P0 + ii;
                    int i = p2 / 14, j = p2 % 14;
                    int t = i + ky - 3, s = j + kx - 3;
                    if (t < 0 || (t & 1) || t >= 14) continue;  // u = t/2 in [0,7)
                    if (s < 0 || (s & 1) || s >= 14) continue;
                    acc[ii] += xr[(t >> 1)*7 + (s >> 1)] * w;
                }
            }
        }
    }
}

// One block = one sample. Whole net in LDS; zero workspace usage. All fp32.
__global__ __launch_bounds__(256)
void fused_k(const float* __restrict__ noise, const int* __restrict__ labels,
             const float* __restrict__ emb,   const float* __restrict__ Wd,
             const float* __restrict__ g1,    const float* __restrict__ b1,
             const float* __restrict__ m1,    const float* __restrict__ v1,
             const float* __restrict__ K1,
             const float* __restrict__ G1, const float* __restrict__ B1,
             const float* __restrict__ M1, const float* __restrict__ V1,
             const float* __restrict__ K2,
             const float* __restrict__ G2, const float* __restrict__ B2,
             const float* __restrict__ M2, const float* __restrict__ V2,
             const float* __restrict__ K3,
             float* __restrict__ out){
    // LDS overlay (liveness): xt2 [0, 54272)  — h1 256xS1 f32, lives conv1->conv2;
    //                         wk  [0, 12800)  — K3 tile, lives conv3 (xt2 dead)
    //                         xt1 [54272, +64872) — xcat 306xS1 f32, lives dense->conv1
    //                         xt3 [54272, +101136) — h2 196x129 f32, lives conv2->conv3
    __shared__ __align__(16) unsigned char smem[54272 + 101136];   // 155,408 B
    __shared__ float xin[152];
    float* xt2 = (float*)smem;
    float* wk  = (float*)smem;
    float* xt1 = (float*)(smem + 54272);
    float* xt3 = (float*)(smem + 54272);

    const int tid = threadIdx.x;
    const int b = blockIdx.x;
    const int c = labels[b] & 15;   // 0..9; mask keeps any garbage in-bounds-ish

    // ---- stage A: gather input vector [noise | emb[label]] ----
    if (tid < 150)
        xin[tid] = (tid < NOISE) ? ldf(noise + b*NOISE + tid)
                                 : ldf(emb + c*EMB + (tid - NOISE));
    __syncthreads();

    // ---- dense 150 -> 12544, BN1, LReLU; thread = channel ci(0..255), 49 positions ----
    {
        float acc[49];
        #pragma unroll
        for (int p = 0; p < 49; p++) acc[p] = 0.f;
        #pragma unroll 1
        for (int k = 0; k < 150; k++){
            float x = xin[k];
            const float* wr = Wd + k*12544 + tid;
            #pragma unroll
            for (int p = 0; p < 49; p++)
                acc[p] += x * ldf(wr + p*256);
        }
        #pragma unroll 1
        for (int p = 0; p < 49; p++){
            int j = p*256 + tid;
            float sc = ldf(g1 + j) * rsqrtf(fmaxf(ldf(v1 + j), 0.f) + BNEPS);
            float y = (acc[p] - ldf(m1 + j))*sc + ldf(b1 + j);
            y = (y >= 0.f) ? y : ALPHA*y;
            xt1[tid*S1 + p] = y;
        }
        if (tid < EMB){
            float v = xin[NOISE + tid];
            #pragma unroll
            for (int p = 0; p < 49; p++) xt1[(256 + tid)*S1 + p] = v;
        }
    }
    __syncthreads();

    // ---- ConvT1: 7x7x306 -> 7x7x256, s=1, pads (2,2); BN+LReLU -> xt2 ----
    {
        float acc[49];
        #pragma unroll
        for (int p = 0; p < 49; p++) acc[p] = 0.f;
        const float* wbase = K1 + (size_t)c*25*CIN1*256 + tid;
        #pragma unroll 1
        for (int ci = 0; ci < CIN1; ci++){
            float xr[49];
            #pragma unroll
            for (int q = 0; q < 49; q++) xr[q] = xt1[ci*S1 + q];
            const float* wci = wbase + ci*256;
            #pragma unroll
            for (int ky = 0; ky < 5; ky++){
                #pragma unroll
                for (int kx = 0; kx < 5; kx++){
                    float w = ldf(wci + (ky*5 + kx)*CIN1*256);
                    #pragma unroll
                    for (int oy = 0; oy < 7; oy++){
                        int iy = oy + ky - 2;
                        if (iy < 0 || iy >= 7) continue;   // folds at compile time
                        #pragma unroll
                        for (int ox = 0; ox < 7; ox++){
                            int ix = ox + kx - 2;
                            if (ix < 0 || ix >= 7) continue;
                            acc[oy*7 + ox] += xr[iy*7 + ix] * w;
                        }
                    }
                }
            }
        }
        float sc = ldf(G1 + c*256 + tid) * rsqrtf(fmaxf(ldf(V1 + c*256 + tid), 0.f) + BNEPS);
        float mm = ldf(M1 + c*256 + tid), bb = ldf(B1 + c*256 + tid);
        #pragma unroll
        for (int p = 0; p < 49; p++){
            float y = (acc[p] - mm)*sc + bb;
            xt2[tid*S1 + p] = (y >= 0.f) ? y : ALPHA*y;
        }
    }
    __syncthreads();   // xt1 dead; xt2 live

    // ---- ConvT2: 7x7x256 -> 14x14x128, s=2, pads (3,2); BN+LReLU -> xt3[p2*129+co] ----
    {
        int co = tid & 127;
        int ph = tid >> 7;          // wave-uniform
        float acc[98];
        #pragma unroll
        for (int i = 0; i < 98; i++) acc[i] = 0.f;
        const float* wbase = K2 + (size_t)c*25*256*128 + co;
        if (ph == 0) conv2_body<0>(xt2, wbase, acc);
        else         conv2_body<98>(xt2, wbase, acc);
        float sc = ldf(G2 + c*128 + co) * rsqrtf(fmaxf(ldf(V2 + c*128 + co), 0.f) + BNEPS);
        float mm = ldf(M2 + c*128 + co), bb = ldf(B2 + c*128 + co);
        #pragma unroll
        for (int ii = 0; ii < 98; ii++){
            int p2 = ph*98 + ii;
            float y = (acc[ii] - mm)*sc + bb;
            xt3[p2*129 + co] = (y >= 0.f) ? y : ALPHA*y;
        }
    }
    __syncthreads();   // xt2 dead; xt3 live

    // ---- ConvT3: 14x14x128 -> 28x28x1, s=2, pads (3,2), tanh ----
    for (int i = tid; i < 3200; i += 256) wk[i] = ldf(K3 + c*3200 + i);
    __syncthreads();
    #pragma unroll 1
    for (int rep = 0; rep < 4; rep++){
        int p3 = tid + rep*256;
        if (p3 < 784){
            int i = p3 / 28, j = p3 - (p3/28)*28;
            float acc = 0.f;
            #pragma unroll
            for (int ky = 0; ky < 5; ky++){
                int t = i + ky - 3;
                if (t < 0 || (t & 1) || t >= 28) continue;   // u in [0,14)
                int u = t >> 1;
                #pragma unroll
                for (int kx = 0; kx < 5; kx++){
                    int s = j + kx - 3;
                    if (s < 0 || (s & 1) || s >= 28) continue;
                    int v = s >> 1;
                    const float* xr = &xt3[(u*14 + v)*129];
                    const float* w = &wk[(ky*5 + kx)*128];
                    #pragma unroll 16
                    for (int cc = 0; cc < 128; cc++)
                        acc += xr[cc] * w[cc];
                }
            }
            out[b*784 + p3] = tanhf(acc);
        }
    }
}

extern "C" void kernel_launch(void* const* d_in, const int* in_sizes, int n_in,
                              void* d_out, int out_size, void* d_ws, size_t ws_size,
                              hipStream_t stream){
    // Reference dtypes are ALL float32 (jnp.float32) -> cast per instructions.
    const float* noise = (const float*)d_in[0];
    const int*   labels= (const int*)  d_in[1];
    const float* emb   = (const float*)d_in[2];
    const float* Wd    = (const float*)d_in[3];
    const float* g1    = (const float*)d_in[4];
    const float* b1    = (const float*)d_in[5];
    const float* m1    = (const float*)d_in[6];
    const float* v1    = (const float*)d_in[7];
    const float* K1    = (const float*)d_in[8];
    const float* G1    = (const float*)d_in[9];
    const float* B1    = (const float*)d_in[10];
    const float* M1    = (const float*)d_in[11];
    const float* V1    = (const float*)d_in[12];
    const float* K2    = (const float*)d_in[13];
    const float* G2    = (const float*)d_in[14];
    const float* B2    = (const float*)d_in[15];
    const float* M2    = (const float*)d_in[16];
    const float* V2    = (const float*)d_in[17];
    const float* K3    = (const float*)d_in[18];
    float* outp = (float*)d_out;

    fused_k<<<512, 256, 0, stream>>>(noise, labels, emb, Wd, g1, b1, m1, v1,
                                     K1, G1, B1, M1, V1,
                                     K2, G2, B2, M2, V2, K3, outp);
}

// Round 5
// 2461.017 us; speedup vs baseline: 1.5428x; 1.5428x over previous
//
#include <hip/hip_runtime.h>

#define NOISE 100
#define EMB   50
#define CIN1  306   // 256 + 50
#define ALPHA 0.3f
#define BNEPS 1e-3f
#define S1    52    // padded row stride (floats): 52*4=208 B = 13*16 -> float4-aligned rows

// ---------------- routing: counting sort of samples by class (order -> ws) ----------------
__global__ void sort_k(const int* __restrict__ labels, int* __restrict__ order){
    __shared__ int cnt[10], offs[10];
    int tid = threadIdx.x;
    if (tid < 10) cnt[tid] = 0;
    __syncthreads();
    int lab = labels[tid];
    atomicAdd(&cnt[lab], 1);
    __syncthreads();
    if (tid == 0){
        int s = 0;
        for (int c = 0; c < 10; c++){ offs[c] = s; s += cnt[c]; }
    }
    __syncthreads();
    int pos = atomicAdd(&offs[lab], 1);
    order[pos] = tid;   // any within-class order is fine: one global result shared by all blocks
}

// ---------------- ConvT1 half: 7x7x306 -> 7x7x256, s=1, pads (2,2) ----------------
// PH=0: output rows 0..3 (28 pos); PH=1: rows 4..6 (21 pos). All masks compile-time.
template<int PH>
__device__ __forceinline__ void conv1_full(const float* __restrict__ xt1,
                                           float* __restrict__ xt2,
                                           const float* __restrict__ wbase,  // K1 + c*25*306*256 + co
                                           float sc, float mm, float bb, int co){
    constexpr int OY0 = PH ? 4 : 0;
    constexpr int NOY = PH ? 3 : 4;
    float acc[NOY*7];
    #pragma unroll
    for (int i = 0; i < NOY*7; i++) acc[i] = 0.f;
    #pragma unroll 1
    for (int ci = 0; ci < CIN1; ci++){
        float xr[49];
        #pragma unroll
        for (int r = 0; r < 12; r++)
            *(float4*)&xr[4*r] = *(const float4*)&xt1[ci*S1 + 4*r];
        xr[48] = xt1[ci*S1 + 48];
        const float* wci = wbase + ci*256;
        #pragma unroll
        for (int ky = 0; ky < 5; ky++){
            #pragma unroll
            for (int kx = 0; kx < 5; kx++){
                float w = wci[(ky*5 + kx)*CIN1*256];
                #pragma unroll
                for (int oy = OY0; oy < OY0 + NOY; oy++){
                    int iy = oy + ky - 2;
                    if (iy < 0 || iy >= 7) continue;        // folds at compile time
                    #pragma unroll
                    for (int ox = 0; ox < 7; ox++){
                        int ix = ox + kx - 2;
                        if (ix < 0 || ix >= 7) continue;
                        acc[(oy - OY0)*7 + ox] += xr[iy*7 + ix] * w;
                    }
                }
            }
        }
    }
    #pragma unroll
    for (int i = 0; i < NOY*7; i++){
        float y = (acc[i] - mm)*sc + bb;
        xt2[co*S1 + OY0*7 + i] = (y >= 0.f) ? y : ALPHA*y;
    }
}

// ---------------- ConvT2 quarter: 7x7x256 -> 14x14x128, s=2, pads (3,2) ----------------
// Q in 0..3: positions p2 in [Q*49, Q*49+49). All masks compile-time.
template<int Q>
__device__ __forceinline__ void conv2_full(const float* __restrict__ xt2,
                                           float* __restrict__ xt3,
                                           const float* __restrict__ wbase,  // K2 + c*25*256*128 + co
                                           float sc, float mm, float bb, int co){
    float acc[49];
    #pragma unroll
    for (int i = 0; i < 49; i++) acc[i] = 0.f;
    #pragma unroll 1
    for (int ci = 0; ci < 256; ci++){
        float xr[49];
        #pragma unroll
        for (int r = 0; r < 12; r++)
            *(float4*)&xr[4*r] = *(const float4*)&xt2[ci*S1 + 4*r];
        xr[48] = xt2[ci*S1 + 48];
        const float* wci = wbase + ci*128;
        #pragma unroll
        for (int ky = 0; ky < 5; ky++){
            #pragma unroll
            for (int kx = 0; kx < 5; kx++){
                float w = wci[(ky*5 + kx)*256*128];
                #pragma unroll
                for (int ii = 0; ii < 49; ii++){
                    int p2 = Q*49 + ii;
                    int i = p2 / 14, j = p2 % 14;
                    int t = i + ky - 3, s = j + kx - 3;
                    if (t < 0 || (t & 1) || t >= 14) continue;   // u = t/2 in [0,7)
                    if (s < 0 || (s & 1) || s >= 14) continue;
                    acc[ii] += xr[(t >> 1)*7 + (s >> 1)] * w;
                }
            }
        }
    }
    #pragma unroll
    for (int ii = 0; ii < 49; ii++){
        int p2 = Q*49 + ii;
        float y = (acc[ii] - mm)*sc + bb;
        xt3[p2*132 + co] = (y >= 0.f) ? y : ALPHA*y;
    }
}

// One block = one sample, 512 threads (8 waves -> 2/SIMD). Whole net in LDS.
__global__ __launch_bounds__(512, 2)
void fused_k(const float* __restrict__ noise, const int* __restrict__ labels,
             const float* __restrict__ emb,   const float* __restrict__ Wd,
             const float* __restrict__ g1,    const float* __restrict__ b1,
             const float* __restrict__ m1,    const float* __restrict__ v1,
             const float* __restrict__ K1,
             const float* __restrict__ G1, const float* __restrict__ B1,
             const float* __restrict__ M1, const float* __restrict__ V1,
             const float* __restrict__ K2,
             const float* __restrict__ G2, const float* __restrict__ B2,
             const float* __restrict__ M2, const float* __restrict__ V2,
             const float* __restrict__ K3,
             const int* __restrict__ order,
             float* __restrict__ out){
    // LDS overlay: region A [0, 53248): xt2 (256xS1 f32, conv1->conv2) then wk (K3, 12.8 KB, conv3)
    //              region B [53248, +103488): xt1 (306xS1 f32, dense->conv1) then xt3 (196x132 f32, conv2->conv3)
    __shared__ __align__(16) unsigned char smem[53248 + 103488];   // 156,736 B
    __shared__ float xin[152];
    float* xt2 = (float*)smem;
    float* wk  = (float*)smem;
    float* xt1 = (float*)(smem + 53248);
    float* xt3 = (float*)(smem + 53248);

    const int tid = threadIdx.x;
    // XCD swizzle: consecutive sorted samples (same class) land on the same XCD -> L2-resident weights
    const int idx = ((blockIdx.x & 7) << 6) | (blockIdx.x >> 3);
    const int b = order[idx];
    const int c = labels[b];

    // ---- stage A: gather input vector [noise | emb[label]] ----
    if (tid < 150)
        xin[tid] = (tid < NOISE) ? noise[b*NOISE + tid]
                                 : emb[c*EMB + (tid - NOISE)];
    __syncthreads();

    // ---- dense 150 -> 12544, BN1, LReLU; thread = (co, pos-half) ----
    {
        const int co = tid & 255;
        const int p0 = (tid >> 8) * 24;      // halves [0,25) and [24,49); p=24 double-written (same value)
        float acc[25];
        #pragma unroll
        for (int i = 0; i < 25; i++) acc[i] = 0.f;
        #pragma unroll 1
        for (int k = 0; k < 150; k++){
            float x = xin[k];
            const float* wr = Wd + k*12544 + p0*256 + co;
            #pragma unroll
            for (int i = 0; i < 25; i++)
                acc[i] += x * wr[i*256];
        }
        #pragma unroll
        for (int i = 0; i < 25; i++){
            int j = (p0 + i)*256 + co;
            float sc = g1[j] * rsqrtf(v1[j] + BNEPS);
            float y = (acc[i] - m1[j])*sc + b1[j];
            y = (y >= 0.f) ? y : ALPHA*y;
            xt1[co*S1 + p0 + i] = y;
        }
        if (tid < EMB){
            float v = xin[NOISE + tid];
            #pragma unroll
            for (int p = 0; p < 49; p++) xt1[(256 + tid)*S1 + p] = v;
        }
    }
    __syncthreads();

    // ---- ConvT1 + BN + LReLU -> xt2 ----
    {
        const int co = tid & 255;
        const int ph = tid >> 8;
        const float* wbase = K1 + (size_t)c*25*CIN1*256 + co;
        float sc = G1[c*256 + co] * rsqrtf(V1[c*256 + co] + BNEPS);
        float mm = M1[c*256 + co], bb = B1[c*256 + co];
        if (ph == 0) conv1_full<0>(xt1, xt2, wbase, sc, mm, bb, co);
        else         conv1_full<1>(xt1, xt2, wbase, sc, mm, bb, co);
    }
    __syncthreads();   // xt1 dead; xt2 live

    // ---- ConvT2 + BN + LReLU -> xt3[p2*132 + co] ----
    {
        const int co = tid & 127;
        const int q  = tid >> 7;
        const float* wbase = K2 + (size_t)c*25*256*128 + co;
        float sc = G2[c*128 + co] * rsqrtf(V2[c*128 + co] + BNEPS);
        float mm = M2[c*128 + co], bb = B2[c*128 + co];
        switch (q){
            case 0: conv2_full<0>(xt2, xt3, wbase, sc, mm, bb, co); break;
            case 1: conv2_full<1>(xt2, xt3, wbase, sc, mm, bb, co); break;
            case 2: conv2_full<2>(xt2, xt3, wbase, sc, mm, bb, co); break;
            default:conv2_full<3>(xt2, xt3, wbase, sc, mm, bb, co); break;
        }
    }
    __syncthreads();   // xt2 dead (conv2 reads done); xt3 live

    // ---- ConvT3: 14x14x128 -> 28x28x1, s=2, pads (3,2), tanh ----
    for (int i = tid; i < 3200; i += 512) wk[i] = K3[c*3200 + i];
    __syncthreads();
    #pragma unroll 1
    for (int rep = 0; rep < 2; rep++){
        int p3 = tid + rep*512;
        if (p3 < 784){
            int i = p3 / 28, j = p3 - (p3/28)*28;
            float acc = 0.f;
            #pragma unroll
            for (int ky = 0; ky < 5; ky++){
                int t = i + ky - 3;
                if (t < 0 || (t & 1) || t >= 28) continue;   // u in [0,14)
                int u = t >> 1;
                #pragma unroll
                for (int kx = 0; kx < 5; kx++){
                    int s = j + kx - 3;
                    if (s < 0 || (s & 1) || s >= 28) continue;
                    int v = s >> 1;
                    const float* xr = &xt3[(u*14 + v)*132];
                    const float* w = &wk[(ky*5 + kx)*128];
                    #pragma unroll
                    for (int cc = 0; cc < 32; cc++){
                        float4 xv = *(const float4*)&xr[4*cc];
                        float4 wv = *(const float4*)&w[4*cc];
                        acc += xv.x*wv.x + xv.y*wv.y + xv.z*wv.z + xv.w*wv.w;
                    }
                }
            }
            out[b*784 + p3] = tanhf(acc);
        }
    }
}

extern "C" void kernel_launch(void* const* d_in, const int* in_sizes, int n_in,
                              void* d_out, int out_size, void* d_ws, size_t ws_size,
                              hipStream_t stream){
    const float* noise = (const float*)d_in[0];
    const int*   labels= (const int*)  d_in[1];
    const float* emb   = (const float*)d_in[2];
    const float* Wd    = (const float*)d_in[3];
    const float* g1    = (const float*)d_in[4];
    const float* b1    = (const float*)d_in[5];
    const float* m1    = (const float*)d_in[6];
    const float* v1    = (const float*)d_in[7];
    const float* K1    = (const float*)d_in[8];
    const float* G1    = (const float*)d_in[9];
    const float* B1    = (const float*)d_in[10];
    const float* M1    = (const float*)d_in[11];
    const float* V1    = (const float*)d_in[12];
    const float* K2    = (const float*)d_in[13];
    const float* G2    = (const float*)d_in[14];
    const float* B2    = (const float*)d_in[15];
    const float* M2    = (const float*)d_in[16];
    const float* V2    = (const float*)d_in[17];
    const float* K3    = (const float*)d_in[18];
    float* outp = (float*)d_out;

    int* order = (int*)d_ws;    // 2 KB of workspace

    sort_k <<<1,   512, 0, stream>>>(labels, order);
    fused_k<<<512, 512, 0, stream>>>(noise, labels, emb, Wd, g1, b1, m1, v1,
                                     K1, G1, B1, M1, V1,
                                     K2, G2, B2, M2, V2, K3, order, outp);
}